// Round 7
// baseline (305.249 us; speedup 1.0000x reference)
//
#include <hip/hip_runtime.h>
#include <math.h>

// Problem constants: B=512, C=50000, D=256.
#define D_DIM 256
#define TM 128
#define TN 128
#define BK 32     // K-tile depth (bf16); 8 K-iterations
#define NBP 392   // padded partial stride (NB=391 -> 392 floats/row)

typedef __attribute__((ext_vector_type(8))) short short8;
typedef __attribute__((ext_vector_type(4))) float floatx4;
typedef unsigned long long u64;

__device__ __forceinline__ unsigned short f2bf(float f) {
    unsigned int u = __float_as_uint(f);
    u += 0x7FFFu + ((u >> 16) & 1u);   // round-to-nearest-even
    return (unsigned short)(u >> 16);
}

// async global->LDS 16B: lane l's 16B lands at ldsbase + l*16 (wave-uniform base)
__device__ __forceinline__ void gload16(const void* g, void* lds) {
    __builtin_amdgcn_global_load_lds(
        (const __attribute__((address_space(1))) unsigned int*)g,
        (__attribute__((address_space(3))) unsigned int*)lds, 16, 0, 0);
}

// ---- prep: loadedmask via binary search (ids sorted) + normalize V,T -> bf16 --------
__global__ void prep(const float* __restrict__ V, const float* __restrict__ T,
                     const int* __restrict__ ids, u64* __restrict__ loadedmask,
                     unsigned short* __restrict__ Vb, unsigned short* __restrict__ Tb,
                     int B, int C, int n_loaded, int WPR) {
    int gtid = blockIdx.x * blockDim.x + threadIdx.x;
    if (gtid < WPR) {   // one thread per mask word; ids is sorted ascending
        int base = gtid << 6;
        int lo = 0, hi = n_loaded;
        while (lo < hi) { int mid = (lo + hi) >> 1; if (ids[mid] < base) lo = mid + 1; else hi = mid; }
        u64 m = 0;
        for (int i = lo; i < n_loaded; ++i) {
            int v = ids[i]; if (v >= base + 64) break;
            m |= 1ull << (v - base);
        }
        loadedmask[gtid] = m;   // full overwrite: no init kernel needed
    }
    int wave = gtid >> 6;
    int lane = threadIdx.x & 63;
    if (wave >= B + C) return;  // whole wave uniform
    bool isV = wave < B;
    const float* src = isV ? (V + (size_t)wave * D_DIM)
                           : (T + (size_t)(wave - B) * D_DIM);
    float4 x = ((const float4*)src)[lane];
    float ss = x.x * x.x + x.y * x.y + x.z * x.z + x.w * x.w;
    #pragma unroll
    for (int off = 32; off > 0; off >>= 1) ss += __shfl_xor(ss, off);
    float nrm = sqrtf(ss);
    float s = isV ? (1.0f / nrm) : (1.0f / (1e-6f + nrm));   // eps on text norms only
    ushort4 o;
    o.x = f2bf(x.x * s); o.y = f2bf(x.y * s);
    o.z = f2bf(x.z * s); o.w = f2bf(x.w * s);
    unsigned short* dst = isV ? (Vb + (size_t)wave * D_DIM)
                              : (Tb + (size_t)(wave - B) * D_DIM);
    ((ushort4*)dst)[lane] = o;
}

// ---- compress: labels (102 MB stream) -> posmask bits (3.2 MB). ----
// One wave covers 1024 cols of one row: 16 independent coalesced loads -> 16 ballots.
__global__ void compress(const int* __restrict__ label, const u64* __restrict__ loadedmask,
                         u64* __restrict__ posmask, int C, int WPR) {
    int row  = blockIdx.y;
    int wir  = blockIdx.x * 4 + (threadIdx.x >> 6);
    int lane = threadIdx.x & 63;
    int w0   = wir * 16;
    if (w0 >= WPR) return;
    const int* lp = label + (size_t)row * C;
    int lab[16];
    #pragma unroll
    for (int j = 0; j < 16; ++j) {       // 16 loads in flight
        int wc  = w0 + j;
        int col = (wc << 6) | lane;
        lab[j] = (wc < WPR && col < C) ? lp[col] : 0;
    }
    #pragma unroll
    for (int j = 0; j < 16; ++j) {
        int wc = w0 + j;
        if (wc < WPR) {
            u64 posw = __ballot(lab[j] != 0) & loadedmask[wc];
            if (lane == 0) posmask[(size_t)row * WPR + wc] = posw;
        }
    }
}

// ---- gemm: bf16 MFMA S-tile + posmask epilogue; near-zero HBM traffic --------------
// grid = (B/TM = 4, NB = 391); m fastest so 4 blocks share one T-tile (L2/L3 reuse).
__global__ __launch_bounds__(256) void gemm_fused(
    const unsigned short* __restrict__ Vb, const unsigned short* __restrict__ Tb,
    const u64* __restrict__ posmask, const u64* __restrict__ loadedmask,
    float* __restrict__ denomP, float* __restrict__ posP, int C, int WPR) {
    __shared__ unsigned short As[TM * BK];   // 8 KB, [row][32] (global_load_lds layout)
    __shared__ unsigned short Bs[TN * BK];   // 8 KB
    __shared__ float sDen[TM], sPos[TM];

    const int tid  = threadIdx.x;
    const int lane = tid & 63;
    const int w    = tid >> 6;
    const int m0 = blockIdx.x * TM;
    const int n0 = blockIdx.y * TN;

    if (tid < TM) { sDen[tid] = 0.f; sPos[tid] = 0.f; }

    // ---- async-staging addresses: wave w covers tile rows [w*32, w*32+32)
    const int sra = lane >> 2;          // row within 16-row group
    const int kc  = (lane & 3) * 8;     // 16B k-chunk
    int ga  = m0 + w * 32 + sra;
    int gb0 = n0 + w * 32 + sra;
    int gb1 = gb0 + 16;
    if (gb0 >= C) gb0 = C - 1;          // OOB rows: valid address, masked in epilogue
    if (gb1 >= C) gb1 = C - 1;
    const unsigned short* gA0 = Vb + (size_t)ga * D_DIM + kc;
    const unsigned short* gA1 = gA0 + (size_t)16 * D_DIM;
    const unsigned short* gB0 = Tb + (size_t)gb0 * D_DIM + kc;
    const unsigned short* gB1 = Tb + (size_t)gb1 * D_DIM + kc;
    unsigned short* lA0 = &As[w * 32 * BK];
    unsigned short* lA1 = lA0 + 16 * BK;
    unsigned short* lB0 = &Bs[w * 32 * BK];
    unsigned short* lB1 = lB0 + 16 * BK;

    // ---- compute mapping: 2x2 waves, each 64x64 via 4x4 frags of 16x16x32
    const int wm = (w >> 1) * 64;
    const int wn = (w & 1) * 64;
    const int fr = lane & 15;
    const int quad = lane >> 4;

    floatx4 acc[4][4];
    #pragma unroll
    for (int mi = 0; mi < 4; mi++)
        #pragma unroll
        for (int ni = 0; ni < 4; ni++) acc[mi][ni] = (floatx4)0.f;

    #pragma unroll
    for (int kt = 0; kt < D_DIM / BK; ++kt) {
        if (kt) __syncthreads();
        const int kb = kt * BK;
        gload16(gA0 + kb, lA0);
        gload16(gA1 + kb, lA1);
        gload16(gB0 + kb, lB0);
        gload16(gB1 + kb, lB1);
        __syncthreads();                // drains vmcnt before barrier
        short8 af[4], bf[4];
        #pragma unroll
        for (int mi = 0; mi < 4; mi++)
            af[mi] = *(const short8*)&As[(wm + mi * 16 + fr) * BK + quad * 8];
        #pragma unroll
        for (int ni = 0; ni < 4; ni++)
            bf[ni] = *(const short8*)&Bs[(wn + ni * 16 + fr) * BK + quad * 8];
        #pragma unroll
        for (int mi = 0; mi < 4; mi++)
            #pragma unroll
            for (int ni = 0; ni < 4; ni++)
                acc[mi][ni] = __builtin_amdgcn_mfma_f32_16x16x32_bf16(
                    af[mi], bf[ni], acc[mi][ni], 0, 0, 0);
    }

    // ---- epilogue: D layout row = quad*4 + reg, col = lane&15 per 16x16 frag.
    const int wcol = (n0 + wn) >> 6;          // this wave's 64-col mask word
    const u64 loadedw = loadedmask[wcol];
    #pragma unroll
    for (int mi = 0; mi < 4; mi++) {
        #pragma unroll
        for (int i = 0; i < 4; i++) {
            const int mloc = wm + mi * 16 + quad * 4 + i;
            const u64 posw = posmask[(size_t)(m0 + mloc) * WPR + wcol];  // L2/L3-hit
            const u64 negw = loadedw & ~posw;
            float den = 0.f, pos = 0.f;
            #pragma unroll
            for (int ni = 0; ni < 4; ni++) {
                const float s = acc[mi][ni][i];
                const int bit = ni * 16 + fr;
                if ((negw >> bit) & 1) den += __expf(s);
                if ((posw >> bit) & 1) pos += s;
            }
            #pragma unroll
            for (int off = 8; off >= 1; off >>= 1) {   // reduce 16-lane quad row
                den += __shfl_xor(den, off);
                pos += __shfl_xor(pos, off);
            }
            if (fr == 0) {
                if (den != 0.f) atomicAdd(&sDen[mloc], den);
                if (pos != 0.f) atomicAdd(&sPos[mloc], pos);
            }
        }
    }
    __syncthreads();
    if (tid < TM) {   // row-major partials: [row][n-block] for coalesced reduce
        denomP[(size_t)(m0 + tid) * NBP + blockIdx.y] = sDen[tid];
        posP[(size_t)(m0 + tid) * NBP + blockIdx.y]   = sPos[tid];
    }
}

// ---- reduce_rows: one wave per row; coalesced partial sums + popcount n_pos ---------
__global__ void reduce_rows(const float* __restrict__ denomP, const float* __restrict__ posP,
                            const u64* __restrict__ posmask, float* __restrict__ pr,
                            int B, int NB, int WPR) {
    int row  = blockIdx.x * 4 + (threadIdx.x >> 6);
    int lane = threadIdx.x & 63;
    if (row >= B) return;
    float den = 0.f, pos = 0.f;
    for (int bn = lane; bn < NB; bn += 64) {   // contiguous within row: coalesced
        den += denomP[(size_t)row * NBP + bn];
        pos += posP[(size_t)row * NBP + bn];
    }
    int cnt = 0;
    for (int j = lane; j < WPR; j += 64)
        cnt += __popcll(posmask[(size_t)row * WPR + j]);
    #pragma unroll
    for (int off = 32; off > 0; off >>= 1) {
        den += __shfl_xor(den, off);
        pos += __shfl_xor(pos, off);
        cnt += __shfl_xor(cnt, off);
    }
    if (lane == 0) pr[row] = logf(den) - pos / (float)cnt;
}

// ---- final mean over B rows ----------------
__global__ void final_mean(const float* __restrict__ pr, float* __restrict__ out, int B) {
    __shared__ float red[512];
    int tid = threadIdx.x;
    red[tid] = (tid < B) ? pr[tid] : 0.f;
    __syncthreads();
    for (int s = 256; s > 0; s >>= 1) {
        if (tid < s) red[tid] += red[tid + s];
        __syncthreads();
    }
    if (tid == 0) out[0] = red[0] / (float)B;
}

extern "C" void kernel_launch(void* const* d_in, const int* in_sizes, int n_in,
                              void* d_out, int out_size, void* d_ws, size_t ws_size,
                              hipStream_t stream) {
    const float* V     = (const float*)d_in[0];
    const float* T     = (const float*)d_in[1];
    const int*   label = (const int*)d_in[2];
    const int*   ids   = (const int*)d_in[3];
    int B = in_sizes[0] / D_DIM;   // 512
    int C = in_sizes[1] / D_DIM;   // 50000
    int n_loaded = in_sizes[3];    // 40000
    int WPR = (C + 63) >> 6;       // mask words per row (782)
    int NB  = (C + TN - 1) / TN;   // n-blocks (391)

    // ws layout (bytes):
    //   0        : pr [512 f]                        (2048)
    //   2048     : loadedmask [782 u64]              (ends 8304; pad to 8320)
    //   8320     : posmask [512*782 u64]             (3,203,072 -> ends 3,211,392)
    //   3211392  : Vb [512*256 bf16]                 (262,144 -> ends 3,473,536)
    //   3473536  : Tb [50000*256 bf16]               (25.6 MB -> ends 29,073,536)
    //   29073536 : denomP [512*NBP f]                (802,816 -> ends 29,876,352)
    //   29876352 : posP                              (ends 30,679,168)
    char* ws = (char*)d_ws;
    float* pr      = (float*)(ws + 0);
    u64*   loadedmask = (u64*)(ws + 2048);
    u64*   posmask    = (u64*)(ws + 8320);
    unsigned short* Vb = (unsigned short*)(ws + 3211392);
    unsigned short* Tb = (unsigned short*)(ws + 3473536);
    float* denomP  = (float*)(ws + 29073536);
    float* posP    = (float*)(ws + 29876352);

    int threads_needed = (B + C) * 64;
    prep<<<(threads_needed + 255) / 256, 256, 0, stream>>>(
        V, T, ids, loadedmask, Vb, Tb, B, C, n_loaded, WPR);

    int wavesPerRow = (WPR + 15) / 16;               // 49
    dim3 cgrid((wavesPerRow + 3) / 4, B);            // (13, 512)
    compress<<<cgrid, 256, 0, stream>>>(label, loadedmask, posmask, C, WPR);

    dim3 grid(B / TM, NB);   // m fastest: 4 blocks share one T-tile
    gemm_fused<<<grid, 256, 0, stream>>>(Vb, Tb, posmask, loadedmask,
                                         denomP, posP, C, WPR);

    reduce_rows<<<(B + 3) / 4, 256, 0, stream>>>(denomP, posP, posmask, pr, B, NB, WPR);

    final_mean<<<1, 512, 0, stream>>>(pr, (float*)d_out, B);
}

// Round 8
// 263.314 us; speedup vs baseline: 1.1593x; 1.1593x over previous
//
#include <hip/hip_runtime.h>
#include <math.h>

// Problem constants: B=512, C=50000, D=256.
#define D_DIM 256
#define TM 128
#define TN 128
#define BK 32     // K-tile depth (bf16); 8 K-iterations
#define NBP 392   // padded partial stride (NB=391)
#define CBPR 7    // compress blocks per row (7*4 waves*2048 cols = 57344 >= 50000)
#define CBLKS (CBPR * 512)   // 3584 compress-role blocks

typedef __attribute__((ext_vector_type(8))) short short8;
typedef __attribute__((ext_vector_type(4))) float floatx4;
typedef unsigned long long u64;

__device__ __forceinline__ unsigned short f2bf(float f) {
    unsigned int u = __float_as_uint(f);
    u += 0x7FFFu + ((u >> 16) & 1u);   // round-to-nearest-even
    return (unsigned short)(u >> 16);
}

// async global->LDS 16B: lane l's 16B lands at ldsbase + l*16 (wave-uniform base)
__device__ __forceinline__ void gload16(const void* g, void* lds) {
    __builtin_amdgcn_global_load_lds(
        (const __attribute__((address_space(1))) unsigned int*)g,
        (__attribute__((address_space(3))) unsigned int*)lds, 16, 0, 0);
}

// ---- kernel 1: fused label-compress (role A) + norms/bf16-convert/loadedmask (role B)
// Two independent HBM streams overlap; posmask holds RAW label bits (loaded-mask AND
// is deferred to consumers, removing the cross-role dependency).
__global__ __launch_bounds__(256) void prep_compress(
    const float* __restrict__ V, const float* __restrict__ T,
    const int* __restrict__ label, const int* __restrict__ ids,
    u64* __restrict__ loadedmask, u64* __restrict__ posmask,
    unsigned short* __restrict__ Vb, unsigned short* __restrict__ Tb,
    float* __restrict__ gaccum, unsigned int* __restrict__ gcount,
    int B, int C, int n_loaded, int WPR) {
    const int bid = blockIdx.x;
    const int tid = threadIdx.x;
    const int lane = tid & 63;

    if (bid < CBLKS) {   // ---- compress role: 102 MB label stream -> 3.2 MB raw posmask
        int row = bid / CBPR;
        int sub = bid - row * CBPR;
        int wl  = tid >> 6;
        int w0col = (sub * 4 + wl) * 2048;     // this wave's 2048-col window
        if (w0col >= C) return;
        const int* lp = label + (size_t)row * C;
        int4 lo[4], hi[4];
        #pragma unroll
        for (int r = 0; r < 4; ++r) {          // 8 x 16B loads in flight
            int c0 = w0col + r * 512 + lane * 8;
            if (c0 < C) {                      // C%8==0: full 8-col chunk valid
                lo[r] = *(const int4*)(lp + c0);
                hi[r] = *(const int4*)(lp + c0 + 4);
            } else {
                lo[r] = make_int4(0, 0, 0, 0);
                hi[r] = make_int4(0, 0, 0, 0);
            }
        }
        #pragma unroll
        for (int r = 0; r < 4; ++r) {
            unsigned int by =
                (lo[r].x ? 1u : 0u) | (lo[r].y ? 2u : 0u) |
                (lo[r].z ? 4u : 0u) | (lo[r].w ? 8u : 0u) |
                (hi[r].x ? 16u : 0u) | (hi[r].y ? 32u : 0u) |
                (hi[r].z ? 64u : 0u) | (hi[r].w ? 128u : 0u);
            u64 wv = (u64)by << (8 * (lane & 7));
            wv |= __shfl_xor(wv, 1);           // OR-butterfly across 8-lane group
            wv |= __shfl_xor(wv, 2);
            wv |= __shfl_xor(wv, 4);
            if ((lane & 7) == 0) {
                int wc = ((w0col + r * 512) >> 6) + (lane >> 3);
                if (wc < WPR) posmask[(size_t)row * WPR + wc] = wv;
            }
        }
        return;
    }

    // ---- prep role: loadedmask (binary search over sorted ids) + normalize -> bf16
    int ptid = (bid - CBLKS) * 256 + tid;
    if (ptid == 0) { *gcount = 0u; *gaccum = 0.f; }   // zero reduce scratch each call
    if (ptid < WPR) {
        int base = ptid << 6;
        int lo = 0, hi = n_loaded;
        while (lo < hi) { int mid = (lo + hi) >> 1; if (ids[mid] < base) lo = mid + 1; else hi = mid; }
        u64 m = 0;
        for (int i = lo; i < n_loaded; ++i) {
            int v = ids[i]; if (v >= base + 64) break;
            m |= 1ull << (v - base);
        }
        loadedmask[ptid] = m;
    }
    int wave = ptid >> 6;
    if (wave >= B + C) return;   // whole wave uniform
    bool isV = wave < B;
    const float* src = isV ? (V + (size_t)wave * D_DIM)
                           : (T + (size_t)(wave - B) * D_DIM);
    float4 x = ((const float4*)src)[lane];
    float ss = x.x * x.x + x.y * x.y + x.z * x.z + x.w * x.w;
    #pragma unroll
    for (int off = 32; off > 0; off >>= 1) ss += __shfl_xor(ss, off);
    float nrm = sqrtf(ss);
    float s = isV ? (1.0f / nrm) : (1.0f / (1e-6f + nrm));   // eps on text norms only
    ushort4 o;
    o.x = f2bf(x.x * s); o.y = f2bf(x.y * s);
    o.z = f2bf(x.z * s); o.w = f2bf(x.w * s);
    unsigned short* dst = isV ? (Vb + (size_t)wave * D_DIM)
                              : (Tb + (size_t)(wave - B) * D_DIM);
    ((ushort4*)dst)[lane] = o;
}

// ---- kernel 2: bf16 MFMA S-tile + raw-posmask epilogue; near-zero HBM traffic ------
// grid = (B/TM = 4, NB = 391); m fastest so 4 blocks share one T-tile (L2/L3 reuse).
__global__ __launch_bounds__(256) void gemm_fused(
    const unsigned short* __restrict__ Vb, const unsigned short* __restrict__ Tb,
    const u64* __restrict__ posmask, const u64* __restrict__ loadedmask,
    float* __restrict__ denomP, float* __restrict__ posP, int C, int WPR) {
    __shared__ unsigned short As[TM * BK];   // 8 KB, [row][32] (global_load_lds layout)
    __shared__ unsigned short Bs[TN * BK];   // 8 KB
    __shared__ float sDen[TM], sPos[TM];

    const int tid  = threadIdx.x;
    const int lane = tid & 63;
    const int w    = tid >> 6;
    const int m0 = blockIdx.x * TM;
    const int n0 = blockIdx.y * TN;

    if (tid < TM) { sDen[tid] = 0.f; sPos[tid] = 0.f; }

    // ---- async-staging addresses: wave w covers tile rows [w*32, w*32+32)
    const int sra = lane >> 2;          // row within 16-row group
    const int kc  = (lane & 3) * 8;     // 16B k-chunk
    int ga  = m0 + w * 32 + sra;
    int gb0 = n0 + w * 32 + sra;
    int gb1 = gb0 + 16;
    if (gb0 >= C) gb0 = C - 1;          // OOB rows: valid address, masked in epilogue
    if (gb1 >= C) gb1 = C - 1;
    const unsigned short* gA0 = Vb + (size_t)ga * D_DIM + kc;
    const unsigned short* gA1 = gA0 + (size_t)16 * D_DIM;
    const unsigned short* gB0 = Tb + (size_t)gb0 * D_DIM + kc;
    const unsigned short* gB1 = Tb + (size_t)gb1 * D_DIM + kc;
    unsigned short* lA0 = &As[w * 32 * BK];
    unsigned short* lA1 = lA0 + 16 * BK;
    unsigned short* lB0 = &Bs[w * 32 * BK];
    unsigned short* lB1 = lB0 + 16 * BK;

    // ---- compute mapping: 2x2 waves, each 64x64 via 4x4 frags of 16x16x32
    const int wm = (w >> 1) * 64;
    const int wn = (w & 1) * 64;
    const int fr = lane & 15;
    const int quad = lane >> 4;

    floatx4 acc[4][4];
    #pragma unroll
    for (int mi = 0; mi < 4; mi++)
        #pragma unroll
        for (int ni = 0; ni < 4; ni++) acc[mi][ni] = (floatx4)0.f;

    #pragma unroll
    for (int kt = 0; kt < D_DIM / BK; ++kt) {
        if (kt) __syncthreads();
        const int kb = kt * BK;
        gload16(gA0 + kb, lA0);
        gload16(gA1 + kb, lA1);
        gload16(gB0 + kb, lB0);
        gload16(gB1 + kb, lB1);
        __syncthreads();                // drains vmcnt before barrier
        short8 af[4], bf[4];
        #pragma unroll
        for (int mi = 0; mi < 4; mi++)
            af[mi] = *(const short8*)&As[(wm + mi * 16 + fr) * BK + quad * 8];
        #pragma unroll
        for (int ni = 0; ni < 4; ni++)
            bf[ni] = *(const short8*)&Bs[(wn + ni * 16 + fr) * BK + quad * 8];
        #pragma unroll
        for (int mi = 0; mi < 4; mi++)
            #pragma unroll
            for (int ni = 0; ni < 4; ni++)
                acc[mi][ni] = __builtin_amdgcn_mfma_f32_16x16x32_bf16(
                    af[mi], bf[ni], acc[mi][ni], 0, 0, 0);
    }

    // ---- epilogue: D layout row = quad*4 + reg, col = lane&15 per 16x16 frag.
    const int wcol = (n0 + wn) >> 6;          // this wave's 64-col mask word
    const u64 loadedw = loadedmask[wcol];
    #pragma unroll
    for (int mi = 0; mi < 4; mi++) {
        #pragma unroll
        for (int i = 0; i < 4; i++) {
            const int mloc = wm + mi * 16 + quad * 4 + i;
            const u64 praw = posmask[(size_t)(m0 + mloc) * WPR + wcol];  // L2/L3-hit
            const u64 posw = praw & loadedw;
            const u64 negw = loadedw & ~praw;
            float den = 0.f, pos = 0.f;
            #pragma unroll
            for (int ni = 0; ni < 4; ni++) {
                const float s = acc[mi][ni][i];
                const int bit = ni * 16 + fr;
                if ((negw >> bit) & 1) den += __expf(s);
                if ((posw >> bit) & 1) pos += s;
            }
            #pragma unroll
            for (int off = 8; off >= 1; off >>= 1) {   // reduce 16-lane quad row
                den += __shfl_xor(den, off);
                pos += __shfl_xor(pos, off);
            }
            if (fr == 0) {
                if (den != 0.f) atomicAdd(&sDen[mloc], den);
                if (pos != 0.f) atomicAdd(&sPos[mloc], pos);
            }
        }
    }
    __syncthreads();
    if (tid < TM) {   // row-major partials: [row][n-block] for coalesced reduce
        denomP[(size_t)(m0 + tid) * NBP + blockIdx.y] = sDen[tid];
        posP[(size_t)(m0 + tid) * NBP + blockIdx.y]   = sPos[tid];
    }
}

// ---- kernel 3: reduce rows + last-block computes the final mean ---------------------
__global__ void reduce_rows(const float* __restrict__ denomP, const float* __restrict__ posP,
                            const u64* __restrict__ posmask, const u64* __restrict__ loadedmask,
                            float* __restrict__ gaccum, unsigned int* __restrict__ gcount,
                            float* __restrict__ out, int B, int NB, int WPR) {
    __shared__ float bsum[4];
    int wv   = threadIdx.x >> 6;
    int row  = blockIdx.x * 4 + wv;
    int lane = threadIdx.x & 63;
    float den = 0.f, pos = 0.f;
    int cnt = 0;
    if (row < B) {
        for (int bn = lane; bn < NB; bn += 64) {   // contiguous within row: coalesced
            den += denomP[(size_t)row * NBP + bn];
            pos += posP[(size_t)row * NBP + bn];
        }
        for (int j = lane; j < WPR; j += 64)
            cnt += __popcll(posmask[(size_t)row * WPR + j] & loadedmask[j]);
        #pragma unroll
        for (int off = 32; off > 0; off >>= 1) {
            den += __shfl_xor(den, off);
            pos += __shfl_xor(pos, off);
            cnt += __shfl_xor(cnt, off);
        }
    }
    if (lane == 0) bsum[wv] = (row < B) ? (logf(den) - pos / (float)cnt) : 0.f;
    __syncthreads();
    if (threadIdx.x == 0) {
        float s = bsum[0] + bsum[1] + bsum[2] + bsum[3];
        atomicAdd(gaccum, s);            // 128 ops total: contention negligible
        __threadfence();
        unsigned int old = atomicAdd(gcount, 1u);
        if (old == gridDim.x - 1) {      // last block: all adds complete & visible
            float tot = atomicAdd(gaccum, 0.0f);   // atomic read-back
            out[0] = tot / (float)B;
        }
    }
}

extern "C" void kernel_launch(void* const* d_in, const int* in_sizes, int n_in,
                              void* d_out, int out_size, void* d_ws, size_t ws_size,
                              hipStream_t stream) {
    const float* V     = (const float*)d_in[0];
    const float* T     = (const float*)d_in[1];
    const int*   label = (const int*)d_in[2];
    const int*   ids   = (const int*)d_in[3];
    int B = in_sizes[0] / D_DIM;   // 512
    int C = in_sizes[1] / D_DIM;   // 50000
    int n_loaded = in_sizes[3];    // 40000
    int WPR = (C + 63) >> 6;       // mask words per row (782)
    int NB  = (C + TN - 1) / TN;   // n-blocks (391)

    // ws layout (bytes):
    //   0        : gaccum [1 f], gcount [1 u32]     (pad to 2048)
    //   2048     : loadedmask [782 u64]             (ends 8304; pad to 8320)
    //   8320     : posmask [512*782 u64]            (3,203,072 -> ends 3,211,392)
    //   3211392  : Vb [512*256 bf16]                (262,144 -> ends 3,473,536)
    //   3473536  : Tb [50000*256 bf16]              (25.6 MB -> ends 29,073,536)
    //   29073536 : denomP [512*NBP f]               (802,816 -> ends 29,876,352)
    //   29876352 : posP                             (ends 30,679,168)
    char* ws = (char*)d_ws;
    float*        gaccum = (float*)(ws + 0);
    unsigned int* gcount = (unsigned int*)(ws + 8);
    u64*   loadedmask = (u64*)(ws + 2048);
    u64*   posmask    = (u64*)(ws + 8320);
    unsigned short* Vb = (unsigned short*)(ws + 3211392);
    unsigned short* Tb = (unsigned short*)(ws + 3473536);
    float* denomP  = (float*)(ws + 29073536);
    float* posP    = (float*)(ws + 29876352);

    int prep_blocks = ((B + C) * 64 + 255) / 256;    // 12628
    prep_compress<<<CBLKS + prep_blocks, 256, 0, stream>>>(
        V, T, label, ids, loadedmask, posmask, Vb, Tb, gaccum, gcount,
        B, C, n_loaded, WPR);

    dim3 grid(B / TM, NB);   // m fastest: 4 blocks share one T-tile
    gemm_fused<<<grid, 256, 0, stream>>>(Vb, Tb, posmask, loadedmask,
                                         denomP, posP, C, WPR);

    reduce_rows<<<(B + 3) / 4, 256, 0, stream>>>(denomP, posP, posmask, loadedmask,
                                                 gaccum, gcount, (float*)d_out, B, NB, WPR);
}